// Round 10
// baseline (295.386 us; speedup 1.0000x reference)
//
#include <hip/hip_runtime.h>
#include <hip/hip_bf16.h>

// Problem dims (fixed)
#define B_   16
#define T_   1024
#define R_   16
#define NP_  64
#define N_   1024      // R_*NP_
#define NL_  20
#define NC_  32
#define H_   256
#define RNL  320       // R_*NL_
#define RNC  512       // R_*NC_
#define BT_  (B_*T_)   // 16384
#define NLP  32        // padded latents per region
#define LPAD (R_*NLP)  // 512 padded lat width

typedef __attribute__((ext_vector_type(8))) short bf16x8;
typedef __attribute__((ext_vector_type(4))) float f32x4;

// ws layout (float offsets)
#define OFF_WCOMB 0
#define OFF_BCOMB (OFF_WCOMB + N_*H_)          // 262144
#define OFF_AMAT  (OFF_BCOMB + H_)             // 262400
#define OFF_CVEC  (OFF_AMAT + N_*RNL)          // 590080
#define OFF_ACC   (OFF_CVEC + RNL)             // 590400
#define OFF_USH   (OFF_ACC + 16)               // 590416: ushort region start
// ushort offsets within region: AmatT[320*1024], WdT[16*64*32], lat_pad[16384*512]
#define UOFF_AMATT 0
#define UOFF_WDT   (UOFF_AMATT + RNL*N_)       // 327680
#define UOFF_LATP  (UOFF_WDT + R_*NP_*NLP)     // 360448

__device__ __forceinline__ ushort f2bf(float f) {
    __hip_bfloat16 h = __float2bfloat16(f);
    return *reinterpret_cast<ushort*>(&h);
}
__device__ __forceinline__ float bf2f(ushort u) {
    union { unsigned u; float f; } v; v.u = ((unsigned)u) << 16;
    return v.f;
}

// W_comb[row][h]; block 0 also zeroes the accumulators.
__global__ __launch_bounds__(256) void k_comb(const float* __restrict__ Wst,
                                              const float* __restrict__ Wu,
                                              const int* __restrict__ keep,
                                              float* __restrict__ Wcomb,
                                              float* __restrict__ acc0) {
    if (blockIdx.x == 0 && threadIdx.x < 2) acc0[threadIdx.x] = 0.f;
    const int g = blockIdx.x * 256 + threadIdx.x;
    const int row = g >> 8, h = g & 255;
    const int r = row >> 6;
    const float* ws = Wst + (size_t)row * NC_;
    const float* wu = Wu + (size_t)(r * NC_) * H_ + h;
    float acc = 0.f;
#pragma unroll
    for (int c = 0; c < NC_; ++c) acc = fmaf(ws[c], wu[c * H_], acc);
    Wcomb[g] = keep[r] ? acc : 0.f;
}

// one block per h (256 blocks)
__global__ __launch_bounds__(256) void k_bcomb(const float* __restrict__ bst,
                                               const float* __restrict__ Wu,
                                               const float* __restrict__ bu,
                                               const int* __restrict__ keep,
                                               float* __restrict__ bcomb) {
    const int h = blockIdx.x;
    const int t = threadIdx.x;
    float acc = 0.f;
#pragma unroll
    for (int i = 0; i < 2; ++i) {
        const int rc = t + i * 256;
        if (keep[rc >> 5]) acc = fmaf(bst[rc], Wu[(size_t)rc * H_ + h], acc);
    }
#pragma unroll
    for (int off = 32; off; off >>= 1) acc += __shfl_down(acc, off);
    __shared__ float red[4];
    if ((t & 63) == 0) red[t >> 6] = acc;
    __syncthreads();
    if (t == 0) bcomb[h] = bu[h] + red[0] + red[1] + red[2] + red[3];
}

// one block per j (320 blocks)
__global__ __launch_bounds__(256) void k_cvec(const float* __restrict__ bcomb,
                                              const float* __restrict__ Wv,
                                              const float* __restrict__ bv,
                                              float* __restrict__ cvec) {
    const int j = blockIdx.x;
    const int t = threadIdx.x;
    float acc = bcomb[t] * Wv[(size_t)t * RNL + j];
#pragma unroll
    for (int off = 32; off; off >>= 1) acc += __shfl_down(acc, off);
    __shared__ float red[4];
    if ((t & 63) == 0) red[t >> 6] = acc;
    __syncthreads();
    if (t == 0) cvec[j] = bv[j] + red[0] + red[1] + red[2] + red[3];
}

// fp32 tiled GEMM (only for Amat = Wcomb @ Wv, 1024x320 K=256)
__global__ __launch_bounds__(256) void gemm_bias(const float* __restrict__ A,
                                                 const float* __restrict__ Bm,
                                                 float* __restrict__ C,
                                                 int M, int N, int K) {
    __shared__ float As[16][132];
    __shared__ float Bs[16][64];
    const int tid = threadIdx.x;
    const int bm = blockIdx.y * 128;
    const int bn = blockIdx.x * 64;
    const int tx = tid & 15, ty = tid >> 4;
    float acc[8][4];
#pragma unroll
    for (int i = 0; i < 8; ++i)
#pragma unroll
        for (int j = 0; j < 4; ++j) acc[i][j] = 0.f;
    for (int k0 = 0; k0 < K; k0 += 16) {
#pragma unroll
        for (int i = 0; i < 2; ++i) {
            const int idx = tid + i * 256;
            const int r = idx >> 2, kq = (idx & 3) << 2;
            const float4 v = *reinterpret_cast<const float4*>(
                A + (size_t)(bm + r) * K + k0 + kq);
            As[kq + 0][r] = v.x; As[kq + 1][r] = v.y;
            As[kq + 2][r] = v.z; As[kq + 3][r] = v.w;
        }
        {
            const int kr = tid >> 4, nq = (tid & 15) << 2;
            *reinterpret_cast<float4*>(&Bs[kr][nq]) =
                *reinterpret_cast<const float4*>(Bm + (size_t)(k0 + kr) * N + bn + nq);
        }
        __syncthreads();
#pragma unroll
        for (int k = 0; k < 16; ++k) {
            float a[8], b[4];
            *reinterpret_cast<float4*>(&a[0]) = *reinterpret_cast<const float4*>(&As[k][ty * 8]);
            *reinterpret_cast<float4*>(&a[4]) = *reinterpret_cast<const float4*>(&As[k][ty * 8 + 4]);
            *reinterpret_cast<float4*>(&b[0]) = *reinterpret_cast<const float4*>(&Bs[k][tx * 4]);
#pragma unroll
            for (int i = 0; i < 8; ++i)
#pragma unroll
                for (int j = 0; j < 4; ++j) acc[i][j] = fmaf(a[i], b[j], acc[i][j]);
        }
        __syncthreads();
    }
#pragma unroll
    for (int i = 0; i < 8; ++i) {
        float4 o;
        o.x = acc[i][0]; o.y = acc[i][1]; o.z = acc[i][2]; o.w = acc[i][3];
        *reinterpret_cast<float4*>(C + (size_t)(bm + ty * 8 + i) * N + bn + tx * 4) = o;
    }
}

// AmatT_bf16[n][k] = bf16(Amat[k][n])
__global__ __launch_bounds__(256) void k_castA(const float* __restrict__ Amat,
                                               ushort* __restrict__ AmatT) {
    const int g = blockIdx.x * 256 + threadIdx.x;
    const int n = g >> 10, k = g & 1023;
    AmatT[g] = f2bf(Amat[(size_t)k * RNL + n]);
}

// WdT_bf[r][n][k] = bf16(Wd[r][k][n]) for k<20, else 0  (B^T layout, K padded to 32)
__global__ __launch_bounds__(256) void k_castWd(const float* __restrict__ Wd,
                                                ushort* __restrict__ WdT) {
    const int g = blockIdx.x * 256 + threadIdx.x;  // 16*64*32 = 32768
    const int k = g & 31, n = (g >> 5) & 63, r = g >> 11;
    WdT[g] = (k < NL_) ? f2bf(Wd[((size_t)r * NL_ + k) * NP_ + n]) : (ushort)0;
}

// lat_pad = bf16(spikes_f32 @ AmatT^T + cvec), region-padded [16384][512].
// BM=128 BN=64 BK=64, 4 waves (2x2). fp32 A cast to bf16 in staging.
__global__ __launch_bounds__(256) void gemm_mfma(const float* __restrict__ A,
                                                 const ushort* __restrict__ Bt,
                                                 const float* __restrict__ bias,
                                                 ushort* __restrict__ latp) {
    __shared__ ushort As[128 * 64];
    __shared__ ushort Bs[64 * 64];
    const int tid = threadIdx.x;
    const int bm = blockIdx.y * 128;
    const int bn = blockIdx.x * 64;
    const int w = tid >> 6;
    const int lane = tid & 63;
    const int wr = w >> 1, wc = w & 1;
    const int l15 = lane & 15, l16 = lane >> 4;

    f32x4 acc[4][2] = {};

    for (int kt = 0; kt < N_; kt += 64) {
        bf16x8 ra[4];
#pragma unroll
        for (int i = 0; i < 4; ++i) {
            const int ci = i * 256 + tid;
            const int row = ci >> 3, cp = ci & 7;
            const float* g = A + (size_t)(bm + row) * N_ + kt + cp * 8;
            const float4 lo = *reinterpret_cast<const float4*>(g);
            const float4 hi = *reinterpret_cast<const float4*>(g + 4);
            bf16x8 v;
            v[0] = (short)f2bf(lo.x); v[1] = (short)f2bf(lo.y);
            v[2] = (short)f2bf(lo.z); v[3] = (short)f2bf(lo.w);
            v[4] = (short)f2bf(hi.x); v[5] = (short)f2bf(hi.y);
            v[6] = (short)f2bf(hi.z); v[7] = (short)f2bf(hi.w);
            ra[i] = v;
        }
        bf16x8 rb[2];
#pragma unroll
        for (int i = 0; i < 2; ++i) {
            const int ci = i * 256 + tid;
            const int n = ci >> 3, cp = ci & 7;
            rb[i] = *reinterpret_cast<const bf16x8*>(
                Bt + (size_t)(bn + n) * N_ + kt + cp * 8);
        }
        __syncthreads();
#pragma unroll
        for (int i = 0; i < 4; ++i) {
            const int ci = i * 256 + tid;
            const int row = ci >> 3, cp = ci & 7;
            *reinterpret_cast<bf16x8*>(As + (row * 8 + (cp ^ (row & 7))) * 8) = ra[i];
        }
#pragma unroll
        for (int i = 0; i < 2; ++i) {
            const int ci = i * 256 + tid;
            const int n = ci >> 3, cp = ci & 7;
            *reinterpret_cast<bf16x8*>(Bs + (n * 8 + (cp ^ (n & 7))) * 8) = rb[i];
        }
        __syncthreads();
#pragma unroll
        for (int ks = 0; ks < 2; ++ks) {
            const int cb = ks * 4 + l16;
            bf16x8 af[4], bfr[2];
#pragma unroll
            for (int mi = 0; mi < 4; ++mi) {
                const int row = wr * 64 + mi * 16 + l15;
                af[mi] = *reinterpret_cast<const bf16x8*>(
                    As + (row * 8 + (cb ^ (row & 7))) * 8);
            }
#pragma unroll
            for (int ni = 0; ni < 2; ++ni) {
                const int n = wc * 32 + ni * 16 + l15;
                bfr[ni] = *reinterpret_cast<const bf16x8*>(
                    Bs + (n * 8 + (cb ^ (n & 7))) * 8);
            }
#pragma unroll
            for (int mi = 0; mi < 4; ++mi)
#pragma unroll
                for (int ni = 0; ni < 2; ++ni)
                    acc[mi][ni] = __builtin_amdgcn_mfma_f32_16x16x32_bf16(
                        af[mi], bfr[ni], acc[mi][ni], 0, 0, 0);
        }
    }
    // epilogue: bf16 store into region-padded layout (col 20..31 of each region unused)
#pragma unroll
    for (int ni = 0; ni < 2; ++ni) {
        const int n = bn + wc * 32 + ni * 16 + l15;
        const int colpad = (n / NL_) * NLP + (n % NL_);
        const float bv = bias[n];
#pragma unroll
        for (int mi = 0; mi < 4; ++mi) {
#pragma unroll
            for (int j = 0; j < 4; ++j) {
                const int m = bm + wr * 64 + mi * 16 + l16 * 4 + j;
                latp[(size_t)m * LPAD + colpad] = f2bf(acc[mi][ni][j] + bv);
            }
        }
    }
}

// MFMA decoder + fused Poisson-NLL partial. No LDS operands, no big reg arrays.
// Grid: BT_/16 blocks x 256 thr (4 waves). Wave w: 16 rows x regions 4w..4w+3.
__global__ __launch_bounds__(256) void k_dec(const ushort* __restrict__ latp,
                                             const ushort* __restrict__ WdT,
                                             const float* __restrict__ bd,
                                             const float* __restrict__ tgt,
                                             float* __restrict__ preds,
                                             float* __restrict__ acc) {
    const int tid = threadIdx.x;
    const int row0 = blockIdx.x * 16;
    const int w = tid >> 6;
    const int lane = tid & 63;
    const int l15 = lane & 15, l16 = lane >> 4;

    float lsum = 0.f;
#pragma unroll
    for (int rr = 0; rr < 4; ++rr) {
        const int r = w * 4 + rr;
        // A-frag: lat_pad[row0+l15][r*32 + l16*8 + j]  (pads x zero-weights = 0)
        const bf16x8 af = *reinterpret_cast<const bf16x8*>(
            latp + (size_t)(row0 + l15) * LPAD + r * NLP + l16 * 8);
        f32x4 pa[4] = {};
#pragma unroll
        for (int ni = 0; ni < 4; ++ni) {
            const bf16x8 bfr = *reinterpret_cast<const bf16x8*>(
                WdT + (((size_t)r * NP_ + ni * 16 + l15) * NLP) + l16 * 8);
            pa[ni] = __builtin_amdgcn_mfma_f32_16x16x32_bf16(af, bfr, pa[ni], 0, 0, 0);
        }
#pragma unroll
        for (int ni = 0; ni < 4; ++ni) {
            const int n = r * NP_ + ni * 16 + l15;
            const float bv = bd[n];
#pragma unroll
            for (int j = 0; j < 4; ++j) {
                const int row = row0 + l16 * 4 + j;
                const float p = pa[ni][j] + bv;
                const size_t gi = (size_t)row * N_ + n;
                const float t = tgt[gi];
                preds[gi] = p;
                lsum += __expf(p) - t * p;
            }
        }
    }
#pragma unroll
    for (int off = 32; off; off >>= 1) lsum += __shfl_down(lsum, off);
    __shared__ float red[4];
    if ((tid & 63) == 0) red[tid >> 6] = lsum;
    __syncthreads();
    if (tid == 0) atomicAdd(acc, red[0] + red[1] + red[2] + red[3]);
}

// reg partial: sum |diff(lat_pad)| over rows with t<T-1 (pad cols diff to exactly 0)
__global__ __launch_bounds__(256) void k_reg(const ushort* __restrict__ latp,
                                             float* __restrict__ acc) {
    const int total8 = BT_ * (LPAD / 8);   // 1,048,576 vec8 positions
    float rsum = 0.f;
    for (int i8 = blockIdx.x * 256 + threadIdx.x; i8 < total8; i8 += gridDim.x * 256) {
        const int row = i8 >> 6;
        if ((row & (T_ - 1)) == T_ - 1) continue;
        const bf16x8 v0 = *reinterpret_cast<const bf16x8*>(latp + (size_t)i8 * 8);
        const bf16x8 v1 = *reinterpret_cast<const bf16x8*>(latp + (size_t)(i8 + 64) * 8);
#pragma unroll
        for (int j = 0; j < 8; ++j)
            rsum += fabsf(bf2f((ushort)v1[j]) - bf2f((ushort)v0[j]));
    }
#pragma unroll
    for (int off = 32; off; off >>= 1) rsum += __shfl_down(rsum, off);
    __shared__ float red[4];
    if ((threadIdx.x & 63) == 0) red[threadIdx.x >> 6] = rsum;
    __syncthreads();
    if (threadIdx.x == 0) atomicAdd(acc + 1, red[0] + red[1] + red[2] + red[3]);
}

__global__ void k_fin(const float* __restrict__ acc, float* __restrict__ out) {
    if (threadIdx.x == 0) {
        out[0] = acc[0] * (1.0f / ((float)BT_ * N_));
        out[1] = acc[1] * (0.1f / ((float)B_ * (T_ - 1) * RNL));
    }
}

extern "C" void kernel_launch(void* const* d_in, const int* in_sizes, int n_in,
                              void* d_out, int out_size, void* d_ws, size_t ws_size,
                              hipStream_t stream) {
    const float* spikes = (const float*)d_in[0];
    const int*   keep   = (const int*)d_in[2];
    const float* Wst    = (const float*)d_in[3];
    const float* bst    = (const float*)d_in[4];
    const float* Wu     = (const float*)d_in[5];
    const float* bu     = (const float*)d_in[6];
    const float* Wv     = (const float*)d_in[7];
    const float* bv     = (const float*)d_in[8];
    const float* Wd     = (const float*)d_in[9];
    const float* bd     = (const float*)d_in[10];
    float* out = (float*)d_out;
    float* ws  = (float*)d_ws;

    float* Wcomb = ws + OFF_WCOMB;
    float* bcomb = ws + OFF_BCOMB;
    float* Amat  = ws + OFF_AMAT;
    float* cvec  = ws + OFF_CVEC;
    float* acc   = ws + OFF_ACC;
    ushort* ush   = (ushort*)(ws + OFF_USH);
    ushort* AmatT = ush + UOFF_AMATT;
    ushort* WdT   = ush + UOFF_WDT;
    ushort* latp  = ush + UOFF_LATP;

    k_comb<<<(N_ * H_) / 256, 256, 0, stream>>>(Wst, Wu, keep, Wcomb, acc);
    k_bcomb<<<H_, 256, 0, stream>>>(bst, Wu, bu, keep, bcomb);
    k_cvec<<<RNL, 256, 0, stream>>>(bcomb, Wv, bv, cvec);
    gemm_bias<<<dim3(RNL / 64, N_ / 128), 256, 0, stream>>>(Wcomb, Wv, Amat, N_, RNL, H_);
    k_castA<<<(RNL * N_) / 256, 256, 0, stream>>>(Amat, AmatT);
    k_castWd<<<(R_ * NP_ * NLP) / 256, 256, 0, stream>>>(Wd, WdT);
    gemm_mfma<<<dim3(RNL / 64, BT_ / 128), 256, 0, stream>>>(spikes, AmatT, cvec, latp);
    k_dec<<<BT_ / 16, 256, 0, stream>>>(latp, WdT, bd, spikes, out + 2, acc);
    k_reg<<<2048, 256, 0, stream>>>(latp, acc);
    k_fin<<<1, 64, 0, stream>>>(acc, out);
}

// Round 11
// 280.692 us; speedup vs baseline: 1.0523x; 1.0523x over previous
//
#include <hip/hip_runtime.h>
#include <hip/hip_bf16.h>

// Problem dims (fixed)
#define B_   16
#define T_   1024
#define R_   16
#define NP_  64
#define N_   1024      // R_*NP_
#define NL_  20
#define NC_  32
#define H_   256
#define RNL  320       // R_*NL_
#define RNC  512       // R_*NC_
#define BT_  (B_*T_)   // 16384
#define NLP  32        // padded latents per region
#define LPAD (R_*NLP)  // 512 padded lat width

typedef __attribute__((ext_vector_type(8))) short bf16x8;
typedef __attribute__((ext_vector_type(4))) float f32x4;

// ws layout (float offsets)
#define OFF_WCOMB 0
#define OFF_BCOMB (OFF_WCOMB + N_*H_)          // 262144
#define OFF_AMAT  (OFF_BCOMB + H_)             // 262400
#define OFF_CVEC  (OFF_AMAT + N_*RNL)          // 590080
#define OFF_ACC   (OFF_CVEC + RNL)             // 590400
#define OFF_USH   (OFF_ACC + 16)               // 590416: ushort region start
#define UOFF_AMATT 0
#define UOFF_WDT   (UOFF_AMATT + RNL*N_)       // 327680
#define UOFF_LATP  (UOFF_WDT + R_*NP_*NLP)     // 360448

__device__ __forceinline__ ushort f2bf(float f) {
    __hip_bfloat16 h = __float2bfloat16(f);
    return *reinterpret_cast<ushort*>(&h);
}
__device__ __forceinline__ float bf2f(ushort u) {
    union { unsigned u; float f; } v; v.u = ((unsigned)u) << 16;
    return v.f;
}

// W_comb[row][h]; block 0 also zeroes the accumulators.
__global__ __launch_bounds__(256) void k_comb(const float* __restrict__ Wst,
                                              const float* __restrict__ Wu,
                                              const int* __restrict__ keep,
                                              float* __restrict__ Wcomb,
                                              float* __restrict__ acc0) {
    if (blockIdx.x == 0 && threadIdx.x < 2) acc0[threadIdx.x] = 0.f;
    const int g = blockIdx.x * 256 + threadIdx.x;
    const int row = g >> 8, h = g & 255;
    const int r = row >> 6;
    const float* ws = Wst + (size_t)row * NC_;
    const float* wu = Wu + (size_t)(r * NC_) * H_ + h;
    float acc = 0.f;
#pragma unroll
    for (int c = 0; c < NC_; ++c) acc = fmaf(ws[c], wu[c * H_], acc);
    Wcomb[g] = keep[r] ? acc : 0.f;
}

// one block per h (256 blocks)
__global__ __launch_bounds__(256) void k_bcomb(const float* __restrict__ bst,
                                               const float* __restrict__ Wu,
                                               const float* __restrict__ bu,
                                               const int* __restrict__ keep,
                                               float* __restrict__ bcomb) {
    const int h = blockIdx.x;
    const int t = threadIdx.x;
    float acc = 0.f;
#pragma unroll
    for (int i = 0; i < 2; ++i) {
        const int rc = t + i * 256;
        if (keep[rc >> 5]) acc = fmaf(bst[rc], Wu[(size_t)rc * H_ + h], acc);
    }
#pragma unroll
    for (int off = 32; off; off >>= 1) acc += __shfl_down(acc, off);
    __shared__ float red[4];
    if ((t & 63) == 0) red[t >> 6] = acc;
    __syncthreads();
    if (t == 0) bcomb[h] = bu[h] + red[0] + red[1] + red[2] + red[3];
}

// one block per j (320 blocks)
__global__ __launch_bounds__(256) void k_cvec(const float* __restrict__ bcomb,
                                              const float* __restrict__ Wv,
                                              const float* __restrict__ bv,
                                              float* __restrict__ cvec) {
    const int j = blockIdx.x;
    const int t = threadIdx.x;
    float acc = bcomb[t] * Wv[(size_t)t * RNL + j];
#pragma unroll
    for (int off = 32; off; off >>= 1) acc += __shfl_down(acc, off);
    __shared__ float red[4];
    if ((t & 63) == 0) red[t >> 6] = acc;
    __syncthreads();
    if (t == 0) cvec[j] = bv[j] + red[0] + red[1] + red[2] + red[3];
}

// fp32 tiled GEMM (only for Amat = Wcomb @ Wv, 1024x320 K=256)
__global__ __launch_bounds__(256) void gemm_bias(const float* __restrict__ A,
                                                 const float* __restrict__ Bm,
                                                 float* __restrict__ C,
                                                 int M, int N, int K) {
    __shared__ float As[16][132];
    __shared__ float Bs[16][64];
    const int tid = threadIdx.x;
    const int bm = blockIdx.y * 128;
    const int bn = blockIdx.x * 64;
    const int tx = tid & 15, ty = tid >> 4;
    float acc[8][4];
#pragma unroll
    for (int i = 0; i < 8; ++i)
#pragma unroll
        for (int j = 0; j < 4; ++j) acc[i][j] = 0.f;
    for (int k0 = 0; k0 < K; k0 += 16) {
#pragma unroll
        for (int i = 0; i < 2; ++i) {
            const int idx = tid + i * 256;
            const int r = idx >> 2, kq = (idx & 3) << 2;
            const float4 v = *reinterpret_cast<const float4*>(
                A + (size_t)(bm + r) * K + k0 + kq);
            As[kq + 0][r] = v.x; As[kq + 1][r] = v.y;
            As[kq + 2][r] = v.z; As[kq + 3][r] = v.w;
        }
        {
            const int kr = tid >> 4, nq = (tid & 15) << 2;
            *reinterpret_cast<float4*>(&Bs[kr][nq]) =
                *reinterpret_cast<const float4*>(Bm + (size_t)(k0 + kr) * N + bn + nq);
        }
        __syncthreads();
#pragma unroll
        for (int k = 0; k < 16; ++k) {
            float a[8], b[4];
            *reinterpret_cast<float4*>(&a[0]) = *reinterpret_cast<const float4*>(&As[k][ty * 8]);
            *reinterpret_cast<float4*>(&a[4]) = *reinterpret_cast<const float4*>(&As[k][ty * 8 + 4]);
            *reinterpret_cast<float4*>(&b[0]) = *reinterpret_cast<const float4*>(&Bs[k][tx * 4]);
#pragma unroll
            for (int i = 0; i < 8; ++i)
#pragma unroll
                for (int j = 0; j < 4; ++j) acc[i][j] = fmaf(a[i], b[j], acc[i][j]);
        }
        __syncthreads();
    }
#pragma unroll
    for (int i = 0; i < 8; ++i) {
        float4 o;
        o.x = acc[i][0]; o.y = acc[i][1]; o.z = acc[i][2]; o.w = acc[i][3];
        *reinterpret_cast<float4*>(C + (size_t)(bm + ty * 8 + i) * N + bn + tx * 4) = o;
    }
}

// AmatT_bf16[n][k] = bf16(Amat[k][n])
__global__ __launch_bounds__(256) void k_castA(const float* __restrict__ Amat,
                                               ushort* __restrict__ AmatT) {
    const int g = blockIdx.x * 256 + threadIdx.x;
    const int n = g >> 10, k = g & 1023;
    AmatT[g] = f2bf(Amat[(size_t)k * RNL + n]);
}

// WdT_bf[r][n][k] = bf16(Wd[r][k][n]) for k<20, else 0
__global__ __launch_bounds__(256) void k_castWd(const float* __restrict__ Wd,
                                                ushort* __restrict__ WdT) {
    const int g = blockIdx.x * 256 + threadIdx.x;  // 32768
    const int k = g & 31, n = (g >> 5) & 63, r = g >> 11;
    WdT[g] = (k < NL_) ? f2bf(Wd[((size_t)r * NL_ + k) * NP_ + n]) : (ushort)0;
}

// lat_pad = bf16(spikes_f32 @ AmatT^T + cvec), region-padded [16384][512].
// BM=64 BN=64 BK=64, grid 1280 (5/CU), 4 waves (2x2, 32x32/wave).
// XCD-aware swizzle: 5 same-row-panel blocks -> same XCD (A fetched once from HBM).
// Reg-staged prefetch: next tile's global loads issued before current tile's MFMAs.
__global__ __launch_bounds__(256) void gemm_mfma(const float* __restrict__ A,
                                                 const ushort* __restrict__ Bt,
                                                 const float* __restrict__ bias,
                                                 ushort* __restrict__ latp) {
    __shared__ ushort As[64 * 64];   // 8 KB, chunk-swizzled
    __shared__ ushort Bs[64 * 64];   // 8 KB
    const int tid = threadIdx.x;
    // bijective XCD swizzle: xcd = id&7 gets row-panels [xcd*32, xcd*32+32)
    const int id = blockIdx.x;           // 0..1279
    const int xcd = id & 7;
    const int j = id >> 3;               // 0..159
    const int bn = (j % 5) * 64;
    const int bm = (xcd * 32 + j / 5) * 64;

    const int w = tid >> 6;
    const int lane = tid & 63;
    const int wr = w >> 1, wc = w & 1;
    const int l15 = lane & 15, l16 = lane >> 4;

    // per-thread staging: 2 A-chunks (8 fp32 each), 2 B-chunks (bf16x8)
    const int arow0 = tid >> 3, acp0 = tid & 7;               // chunk ci = tid
    const int arow1 = (tid + 256) >> 3, acp1 = tid & 7;       // chunk ci = tid+256
    const float* gA0 = A + (size_t)(bm + arow0) * N_ + acp0 * 8;
    const float* gA1 = A + (size_t)(bm + arow1) * N_ + acp1 * 8;
    const ushort* gB0 = Bt + (size_t)(bn + arow0) * N_ + acp0 * 8;
    const ushort* gB1 = Bt + (size_t)(bn + arow1) * N_ + acp1 * 8;
    // LDS byte-linear targets (swizzled chunk index, rule #21 both-sides involution)
    ushort* lA0 = As + (arow0 * 8 + (acp0 ^ (arow0 & 7))) * 8;
    ushort* lA1 = As + (arow1 * 8 + (acp1 ^ (arow1 & 7))) * 8;
    ushort* lB0 = Bs + (arow0 * 8 + (acp0 ^ (arow0 & 7))) * 8;
    ushort* lB1 = Bs + (arow1 * 8 + (acp1 ^ (arow1 & 7))) * 8;

    f32x4 acc[2][2] = {};

    float4 a00, a01, a10, a11;
    bf16x8 rb0, rb1;
    // initial tile load (kt=0)
    a00 = *reinterpret_cast<const float4*>(gA0);
    a01 = *reinterpret_cast<const float4*>(gA0 + 4);
    a10 = *reinterpret_cast<const float4*>(gA1);
    a11 = *reinterpret_cast<const float4*>(gA1 + 4);
    rb0 = *reinterpret_cast<const bf16x8*>(gB0);
    rb1 = *reinterpret_cast<const bf16x8*>(gB1);

    for (int kt = 0; kt < N_ / 64; ++kt) {
        __syncthreads();   // previous compute done reading LDS
        {
            bf16x8 v;
            v[0] = (short)f2bf(a00.x); v[1] = (short)f2bf(a00.y);
            v[2] = (short)f2bf(a00.z); v[3] = (short)f2bf(a00.w);
            v[4] = (short)f2bf(a01.x); v[5] = (short)f2bf(a01.y);
            v[6] = (short)f2bf(a01.z); v[7] = (short)f2bf(a01.w);
            *reinterpret_cast<bf16x8*>(lA0) = v;
            v[0] = (short)f2bf(a10.x); v[1] = (short)f2bf(a10.y);
            v[2] = (short)f2bf(a10.z); v[3] = (short)f2bf(a10.w);
            v[4] = (short)f2bf(a11.x); v[5] = (short)f2bf(a11.y);
            v[6] = (short)f2bf(a11.z); v[7] = (short)f2bf(a11.w);
            *reinterpret_cast<bf16x8*>(lA1) = v;
            *reinterpret_cast<bf16x8*>(lB0) = rb0;
            *reinterpret_cast<bf16x8*>(lB1) = rb1;
        }
        __syncthreads();   // LDS ready
        // prefetch next tile while computing this one
        if (kt + 1 < N_ / 64) {
            const int ko = (kt + 1) * 64;
            a00 = *reinterpret_cast<const float4*>(gA0 + ko);
            a01 = *reinterpret_cast<const float4*>(gA0 + ko + 4);
            a10 = *reinterpret_cast<const float4*>(gA1 + ko);
            a11 = *reinterpret_cast<const float4*>(gA1 + ko + 4);
            rb0 = *reinterpret_cast<const bf16x8*>(gB0 + ko);
            rb1 = *reinterpret_cast<const bf16x8*>(gB1 + ko);
        }
#pragma unroll
        for (int ks = 0; ks < 2; ++ks) {
            const int cb = ks * 4 + l16;
            bf16x8 af[2], bfr[2];
#pragma unroll
            for (int mi = 0; mi < 2; ++mi) {
                const int row = wr * 32 + mi * 16 + l15;
                af[mi] = *reinterpret_cast<const bf16x8*>(
                    As + (row * 8 + (cb ^ (row & 7))) * 8);
            }
#pragma unroll
            for (int ni = 0; ni < 2; ++ni) {
                const int n = wc * 32 + ni * 16 + l15;
                bfr[ni] = *reinterpret_cast<const bf16x8*>(
                    Bs + (n * 8 + (cb ^ (n & 7))) * 8);
            }
#pragma unroll
            for (int mi = 0; mi < 2; ++mi)
#pragma unroll
                for (int ni = 0; ni < 2; ++ni)
                    acc[mi][ni] = __builtin_amdgcn_mfma_f32_16x16x32_bf16(
                        af[mi], bfr[ni], acc[mi][ni], 0, 0, 0);
        }
    }
    // epilogue: bf16 store into region-padded layout
#pragma unroll
    for (int ni = 0; ni < 2; ++ni) {
        const int n = bn + wc * 32 + ni * 16 + l15;
        const int colpad = (n / NL_) * NLP + (n % NL_);
        const float bv = bias[n];
#pragma unroll
        for (int mi = 0; mi < 2; ++mi) {
#pragma unroll
            for (int jj = 0; jj < 4; ++jj) {
                const int m = bm + wr * 32 + mi * 16 + l16 * 4 + jj;
                latp[(size_t)m * LPAD + colpad] = f2bf(acc[mi][ni][jj] + bv);
            }
        }
    }
}

// MFMA decoder + fused Poisson-NLL partial.
__global__ __launch_bounds__(256) void k_dec(const ushort* __restrict__ latp,
                                             const ushort* __restrict__ WdT,
                                             const float* __restrict__ bd,
                                             const float* __restrict__ tgt,
                                             float* __restrict__ preds,
                                             float* __restrict__ acc) {
    const int tid = threadIdx.x;
    const int row0 = blockIdx.x * 16;
    const int w = tid >> 6;
    const int lane = tid & 63;
    const int l15 = lane & 15, l16 = lane >> 4;

    float lsum = 0.f;
#pragma unroll
    for (int rr = 0; rr < 4; ++rr) {
        const int r = w * 4 + rr;
        const bf16x8 af = *reinterpret_cast<const bf16x8*>(
            latp + (size_t)(row0 + l15) * LPAD + r * NLP + l16 * 8);
        f32x4 pa[4] = {};
#pragma unroll
        for (int ni = 0; ni < 4; ++ni) {
            const bf16x8 bfr = *reinterpret_cast<const bf16x8*>(
                WdT + (((size_t)r * NP_ + ni * 16 + l15) * NLP) + l16 * 8);
            pa[ni] = __builtin_amdgcn_mfma_f32_16x16x32_bf16(af, bfr, pa[ni], 0, 0, 0);
        }
#pragma unroll
        for (int ni = 0; ni < 4; ++ni) {
            const int n = r * NP_ + ni * 16 + l15;
            const float bv = bd[n];
#pragma unroll
            for (int jj = 0; jj < 4; ++jj) {
                const int row = row0 + l16 * 4 + jj;
                const float p = pa[ni][jj] + bv;
                const size_t gi = (size_t)row * N_ + n;
                const float t = tgt[gi];
                preds[gi] = p;
                lsum += __expf(p) - t * p;
            }
        }
    }
#pragma unroll
    for (int off = 32; off; off >>= 1) lsum += __shfl_down(lsum, off);
    __shared__ float red[4];
    if ((tid & 63) == 0) red[tid >> 6] = lsum;
    __syncthreads();
    if (tid == 0) atomicAdd(acc, red[0] + red[1] + red[2] + red[3]);
}

// reg partial: sum |diff(lat_pad)| (pad cols diff to exactly 0)
__global__ __launch_bounds__(256) void k_reg(const ushort* __restrict__ latp,
                                             float* __restrict__ acc) {
    const int total8 = BT_ * (LPAD / 8);
    float rsum = 0.f;
    for (int i8 = blockIdx.x * 256 + threadIdx.x; i8 < total8; i8 += gridDim.x * 256) {
        const int row = i8 >> 6;
        if ((row & (T_ - 1)) == T_ - 1) continue;
        const bf16x8 v0 = *reinterpret_cast<const bf16x8*>(latp + (size_t)i8 * 8);
        const bf16x8 v1 = *reinterpret_cast<const bf16x8*>(latp + (size_t)(i8 + 64) * 8);
#pragma unroll
        for (int jj = 0; jj < 8; ++jj)
            rsum += fabsf(bf2f((ushort)v1[jj]) - bf2f((ushort)v0[jj]));
    }
#pragma unroll
    for (int off = 32; off; off >>= 1) rsum += __shfl_down(rsum, off);
    __shared__ float red[4];
    if ((threadIdx.x & 63) == 0) red[threadIdx.x >> 6] = rsum;
    __syncthreads();
    if (threadIdx.x == 0) atomicAdd(acc + 1, red[0] + red[1] + red[2] + red[3]);
}

__global__ void k_fin(const float* __restrict__ acc, float* __restrict__ out) {
    if (threadIdx.x == 0) {
        out[0] = acc[0] * (1.0f / ((float)BT_ * N_));
        out[1] = acc[1] * (0.1f / ((float)B_ * (T_ - 1) * RNL));
    }
}

extern "C" void kernel_launch(void* const* d_in, const int* in_sizes, int n_in,
                              void* d_out, int out_size, void* d_ws, size_t ws_size,
                              hipStream_t stream) {
    const float* spikes = (const float*)d_in[0];
    const int*   keep   = (const int*)d_in[2];
    const float* Wst    = (const float*)d_in[3];
    const float* bst    = (const float*)d_in[4];
    const float* Wu     = (const float*)d_in[5];
    const float* bu     = (const float*)d_in[6];
    const float* Wv     = (const float*)d_in[7];
    const float* bv     = (const float*)d_in[8];
    const float* Wd     = (const float*)d_in[9];
    const float* bd     = (const float*)d_in[10];
    float* out = (float*)d_out;
    float* ws  = (float*)d_ws;

    float* Wcomb = ws + OFF_WCOMB;
    float* bcomb = ws + OFF_BCOMB;
    float* Amat  = ws + OFF_AMAT;
    float* cvec  = ws + OFF_CVEC;
    float* acc   = ws + OFF_ACC;
    ushort* ush   = (ushort*)(ws + OFF_USH);
    ushort* AmatT = ush + UOFF_AMATT;
    ushort* WdT   = ush + UOFF_WDT;
    ushort* latp  = ush + UOFF_LATP;

    k_comb<<<(N_ * H_) / 256, 256, 0, stream>>>(Wst, Wu, keep, Wcomb, acc);
    k_bcomb<<<H_, 256, 0, stream>>>(bst, Wu, bu, keep, bcomb);
    k_cvec<<<RNL, 256, 0, stream>>>(bcomb, Wv, bv, cvec);
    gemm_bias<<<dim3(RNL / 64, N_ / 128), 256, 0, stream>>>(Wcomb, Wv, Amat, N_, RNL, H_);
    k_castA<<<(RNL * N_) / 256, 256, 0, stream>>>(Amat, AmatT);
    k_castWd<<<(R_ * NP_ * NLP) / 256, 256, 0, stream>>>(Wd, WdT);
    gemm_mfma<<<1280, 256, 0, stream>>>(spikes, AmatT, cvec, latp);
    k_dec<<<BT_ / 16, 256, 0, stream>>>(latp, WdT, bd, spikes, out + 2, acc);
    k_reg<<<2048, 256, 0, stream>>>(latp, acc);
    k_fin<<<1, 64, 0, stream>>>(acc, out);
}

// Round 12
// 272.014 us; speedup vs baseline: 1.0859x; 1.0319x over previous
//
#include <hip/hip_runtime.h>
#include <hip/hip_bf16.h>

// Problem dims (fixed)
#define B_   16
#define T_   1024
#define R_   16
#define NP_  64
#define N_   1024      // R_*NP_
#define NL_  20
#define NC_  32
#define H_   256
#define RNL  320       // R_*NL_
#define RNC  512       // R_*NC_
#define BT_  (B_*T_)   // 16384
#define NLP  32        // padded latents per region
#define LPAD (R_*NLP)  // 512 padded lat width

typedef __attribute__((ext_vector_type(8))) short bf16x8;
typedef __attribute__((ext_vector_type(4))) float f32x4;

// ws layout (float offsets)
#define OFF_WCOMB 0
#define OFF_BCOMB (OFF_WCOMB + N_*H_)          // 262144
#define OFF_AMAT  (OFF_BCOMB + H_)             // 262400
#define OFF_CVEC  (OFF_AMAT + N_*RNL)          // 590080
#define OFF_ACC   (OFF_CVEC + RNL)             // 590400
#define OFF_USH   (OFF_ACC + 16)               // 590416: ushort region start
#define UOFF_AMATT 0
#define UOFF_WDT   (UOFF_AMATT + RNL*N_)       // 327680
#define UOFF_LATP  (UOFF_WDT + R_*NP_*NLP)     // 360448

__device__ __forceinline__ ushort f2bf(float f) {
    __hip_bfloat16 h = __float2bfloat16(f);
    return *reinterpret_cast<ushort*>(&h);
}
__device__ __forceinline__ float bf2f(ushort u) {
    union { unsigned u; float f; } v; v.u = ((unsigned)u) << 16;
    return v.f;
}

// W_comb[row][h]; block 0 also zeroes the accumulators.
__global__ __launch_bounds__(256) void k_comb(const float* __restrict__ Wst,
                                              const float* __restrict__ Wu,
                                              const int* __restrict__ keep,
                                              float* __restrict__ Wcomb,
                                              float* __restrict__ acc0) {
    if (blockIdx.x == 0 && threadIdx.x < 2) acc0[threadIdx.x] = 0.f;
    const int g = blockIdx.x * 256 + threadIdx.x;
    const int row = g >> 8, h = g & 255;
    const int r = row >> 6;
    const float* ws = Wst + (size_t)row * NC_;
    const float* wu = Wu + (size_t)(r * NC_) * H_ + h;
    float acc = 0.f;
#pragma unroll
    for (int c = 0; c < NC_; ++c) acc = fmaf(ws[c], wu[c * H_], acc);
    Wcomb[g] = keep[r] ? acc : 0.f;
}

// one block per h (256 blocks)
__global__ __launch_bounds__(256) void k_bcomb(const float* __restrict__ bst,
                                               const float* __restrict__ Wu,
                                               const float* __restrict__ bu,
                                               const int* __restrict__ keep,
                                               float* __restrict__ bcomb) {
    const int h = blockIdx.x;
    const int t = threadIdx.x;
    float acc = 0.f;
#pragma unroll
    for (int i = 0; i < 2; ++i) {
        const int rc = t + i * 256;
        if (keep[rc >> 5]) acc = fmaf(bst[rc], Wu[(size_t)rc * H_ + h], acc);
    }
#pragma unroll
    for (int off = 32; off; off >>= 1) acc += __shfl_down(acc, off);
    __shared__ float red[4];
    if ((t & 63) == 0) red[t >> 6] = acc;
    __syncthreads();
    if (t == 0) bcomb[h] = bu[h] + red[0] + red[1] + red[2] + red[3];
}

// one block per j (320 blocks)
__global__ __launch_bounds__(256) void k_cvec(const float* __restrict__ bcomb,
                                              const float* __restrict__ Wv,
                                              const float* __restrict__ bv,
                                              float* __restrict__ cvec) {
    const int j = blockIdx.x;
    const int t = threadIdx.x;
    float acc = bcomb[t] * Wv[(size_t)t * RNL + j];
#pragma unroll
    for (int off = 32; off; off >>= 1) acc += __shfl_down(acc, off);
    __shared__ float red[4];
    if ((t & 63) == 0) red[t >> 6] = acc;
    __syncthreads();
    if (t == 0) cvec[j] = bv[j] + red[0] + red[1] + red[2] + red[3];
}

// fp32 tiled GEMM (only for Amat = Wcomb @ Wv, 1024x320 K=256)
__global__ __launch_bounds__(256) void gemm_bias(const float* __restrict__ A,
                                                 const float* __restrict__ Bm,
                                                 float* __restrict__ C,
                                                 int M, int N, int K) {
    __shared__ float As[16][132];
    __shared__ float Bs[16][64];
    const int tid = threadIdx.x;
    const int bm = blockIdx.y * 128;
    const int bn = blockIdx.x * 64;
    const int tx = tid & 15, ty = tid >> 4;
    float acc[8][4];
#pragma unroll
    for (int i = 0; i < 8; ++i)
#pragma unroll
        for (int j = 0; j < 4; ++j) acc[i][j] = 0.f;
    for (int k0 = 0; k0 < K; k0 += 16) {
#pragma unroll
        for (int i = 0; i < 2; ++i) {
            const int idx = tid + i * 256;
            const int r = idx >> 2, kq = (idx & 3) << 2;
            const float4 v = *reinterpret_cast<const float4*>(
                A + (size_t)(bm + r) * K + k0 + kq);
            As[kq + 0][r] = v.x; As[kq + 1][r] = v.y;
            As[kq + 2][r] = v.z; As[kq + 3][r] = v.w;
        }
        {
            const int kr = tid >> 4, nq = (tid & 15) << 2;
            *reinterpret_cast<float4*>(&Bs[kr][nq]) =
                *reinterpret_cast<const float4*>(Bm + (size_t)(k0 + kr) * N + bn + nq);
        }
        __syncthreads();
#pragma unroll
        for (int k = 0; k < 16; ++k) {
            float a[8], b[4];
            *reinterpret_cast<float4*>(&a[0]) = *reinterpret_cast<const float4*>(&As[k][ty * 8]);
            *reinterpret_cast<float4*>(&a[4]) = *reinterpret_cast<const float4*>(&As[k][ty * 8 + 4]);
            *reinterpret_cast<float4*>(&b[0]) = *reinterpret_cast<const float4*>(&Bs[k][tx * 4]);
#pragma unroll
            for (int i = 0; i < 8; ++i)
#pragma unroll
                for (int j = 0; j < 4; ++j) acc[i][j] = fmaf(a[i], b[j], acc[i][j]);
        }
        __syncthreads();
    }
#pragma unroll
    for (int i = 0; i < 8; ++i) {
        float4 o;
        o.x = acc[i][0]; o.y = acc[i][1]; o.z = acc[i][2]; o.w = acc[i][3];
        *reinterpret_cast<float4*>(C + (size_t)(bm + ty * 8 + i) * N + bn + tx * 4) = o;
    }
}

// AmatT_bf16[n][k] = bf16(Amat[k][n])
__global__ __launch_bounds__(256) void k_castA(const float* __restrict__ Amat,
                                               ushort* __restrict__ AmatT) {
    const int g = blockIdx.x * 256 + threadIdx.x;
    const int n = g >> 10, k = g & 1023;
    AmatT[g] = f2bf(Amat[(size_t)k * RNL + n]);
}

// WdT_bf[r][n][k] = bf16(Wd[r][k][n]) for k<20, else 0
__global__ __launch_bounds__(256) void k_castWd(const float* __restrict__ Wd,
                                                ushort* __restrict__ WdT) {
    const int g = blockIdx.x * 256 + threadIdx.x;  // 32768
    const int k = g & 31, n = (g >> 5) & 63, r = g >> 11;
    WdT[g] = (k < NL_) ? f2bf(Wd[((size_t)r * NL_ + k) * NP_ + n]) : (ushort)0;
}

// lat_pad = bf16(spikes_f32 @ AmatT^T + cvec), region-padded [16384][512].
// BM=64 BN=64 BK=64, grid 1280 (5/CU), 4 waves (2x2, 32x32/wave).
// XCD-aware swizzle + reg-staged prefetch.
__global__ __launch_bounds__(256) void gemm_mfma(const float* __restrict__ A,
                                                 const ushort* __restrict__ Bt,
                                                 const float* __restrict__ bias,
                                                 ushort* __restrict__ latp) {
    __shared__ ushort As[64 * 64];
    __shared__ ushort Bs[64 * 64];
    const int tid = threadIdx.x;
    const int id = blockIdx.x;           // 0..1279
    const int xcd = id & 7;
    const int j = id >> 3;               // 0..159
    const int bn = (j % 5) * 64;
    const int bm = (xcd * 32 + j / 5) * 64;

    const int w = tid >> 6;
    const int lane = tid & 63;
    const int wr = w >> 1, wc = w & 1;
    const int l15 = lane & 15, l16 = lane >> 4;

    const int arow0 = tid >> 3, acp0 = tid & 7;
    const int arow1 = (tid + 256) >> 3, acp1 = tid & 7;
    const float* gA0 = A + (size_t)(bm + arow0) * N_ + acp0 * 8;
    const float* gA1 = A + (size_t)(bm + arow1) * N_ + acp1 * 8;
    const ushort* gB0 = Bt + (size_t)(bn + arow0) * N_ + acp0 * 8;
    const ushort* gB1 = Bt + (size_t)(bn + arow1) * N_ + acp1 * 8;
    ushort* lA0 = As + (arow0 * 8 + (acp0 ^ (arow0 & 7))) * 8;
    ushort* lA1 = As + (arow1 * 8 + (acp1 ^ (arow1 & 7))) * 8;
    ushort* lB0 = Bs + (arow0 * 8 + (acp0 ^ (arow0 & 7))) * 8;
    ushort* lB1 = Bs + (arow1 * 8 + (acp1 ^ (arow1 & 7))) * 8;

    f32x4 acc[2][2] = {};

    float4 a00, a01, a10, a11;
    bf16x8 rb0, rb1;
    a00 = *reinterpret_cast<const float4*>(gA0);
    a01 = *reinterpret_cast<const float4*>(gA0 + 4);
    a10 = *reinterpret_cast<const float4*>(gA1);
    a11 = *reinterpret_cast<const float4*>(gA1 + 4);
    rb0 = *reinterpret_cast<const bf16x8*>(gB0);
    rb1 = *reinterpret_cast<const bf16x8*>(gB1);

    for (int kt = 0; kt < N_ / 64; ++kt) {
        __syncthreads();
        {
            bf16x8 v;
            v[0] = (short)f2bf(a00.x); v[1] = (short)f2bf(a00.y);
            v[2] = (short)f2bf(a00.z); v[3] = (short)f2bf(a00.w);
            v[4] = (short)f2bf(a01.x); v[5] = (short)f2bf(a01.y);
            v[6] = (short)f2bf(a01.z); v[7] = (short)f2bf(a01.w);
            *reinterpret_cast<bf16x8*>(lA0) = v;
            v[0] = (short)f2bf(a10.x); v[1] = (short)f2bf(a10.y);
            v[2] = (short)f2bf(a10.z); v[3] = (short)f2bf(a10.w);
            v[4] = (short)f2bf(a11.x); v[5] = (short)f2bf(a11.y);
            v[6] = (short)f2bf(a11.z); v[7] = (short)f2bf(a11.w);
            *reinterpret_cast<bf16x8*>(lA1) = v;
            *reinterpret_cast<bf16x8*>(lB0) = rb0;
            *reinterpret_cast<bf16x8*>(lB1) = rb1;
        }
        __syncthreads();
        if (kt + 1 < N_ / 64) {
            const int ko = (kt + 1) * 64;
            a00 = *reinterpret_cast<const float4*>(gA0 + ko);
            a01 = *reinterpret_cast<const float4*>(gA0 + ko + 4);
            a10 = *reinterpret_cast<const float4*>(gA1 + ko);
            a11 = *reinterpret_cast<const float4*>(gA1 + ko + 4);
            rb0 = *reinterpret_cast<const bf16x8*>(gB0 + ko);
            rb1 = *reinterpret_cast<const bf16x8*>(gB1 + ko);
        }
#pragma unroll
        for (int ks = 0; ks < 2; ++ks) {
            const int cb = ks * 4 + l16;
            bf16x8 af[2], bfr[2];
#pragma unroll
            for (int mi = 0; mi < 2; ++mi) {
                const int row = wr * 32 + mi * 16 + l15;
                af[mi] = *reinterpret_cast<const bf16x8*>(
                    As + (row * 8 + (cb ^ (row & 7))) * 8);
            }
#pragma unroll
            for (int ni = 0; ni < 2; ++ni) {
                const int n = wc * 32 + ni * 16 + l15;
                bfr[ni] = *reinterpret_cast<const bf16x8*>(
                    Bs + (n * 8 + (cb ^ (n & 7))) * 8);
            }
#pragma unroll
            for (int mi = 0; mi < 2; ++mi)
#pragma unroll
                for (int ni = 0; ni < 2; ++ni)
                    acc[mi][ni] = __builtin_amdgcn_mfma_f32_16x16x32_bf16(
                        af[mi], bfr[ni], acc[mi][ni], 0, 0, 0);
        }
    }
#pragma unroll
    for (int ni = 0; ni < 2; ++ni) {
        const int n = bn + wc * 32 + ni * 16 + l15;
        const int colpad = (n / NL_) * NLP + (n % NL_);
        const float bv = bias[n];
#pragma unroll
        for (int mi = 0; mi < 2; ++mi) {
#pragma unroll
            for (int jj = 0; jj < 4; ++jj) {
                const int m = bm + wr * 32 + mi * 16 + l16 * 4 + jj;
                latp[(size_t)m * LPAD + colpad] = f2bf(acc[mi][ni][jj] + bv);
            }
        }
    }
}

// MFMA decoder + fused Poisson-NLL partial, LDS-transposed coalesced epilogue.
// R11: preds written as 64B partial lines -> WRITE_SIZE 109MB for 67MB output.
// Now: per-wave 16x64 fp32 tile bounced through padded LDS ([16][68], 2-way max),
// written back as float4/lane (256B per 16-lane group, full cachelines).
__global__ __launch_bounds__(256) void k_dec(const ushort* __restrict__ latp,
                                             const ushort* __restrict__ WdT,
                                             const float* __restrict__ bd,
                                             const float* __restrict__ tgt,
                                             float* __restrict__ preds,
                                             float* __restrict__ acc) {
    __shared__ float pt[4][16][68];   // per-wave padded tile, 17.4 KB
    const int tid = threadIdx.x;
    const int row0 = blockIdx.x * 16;
    const int w = tid >> 6;
    const int lane = tid & 63;
    const int l15 = lane & 15, l16 = lane >> 4;

    float lsum = 0.f;
#pragma unroll
    for (int rr = 0; rr < 4; ++rr) {
        const int r = w * 4 + rr;
        // A-frag: lat_pad[row0+l15][r*32 + l16*8 + j]  (pads x zero-weights = 0)
        const bf16x8 af = *reinterpret_cast<const bf16x8*>(
            latp + (size_t)(row0 + l15) * LPAD + r * NLP + l16 * 8);
        f32x4 pa[4] = {};
#pragma unroll
        for (int ni = 0; ni < 4; ++ni) {
            const bf16x8 bfr = *reinterpret_cast<const bf16x8*>(
                WdT + (((size_t)r * NP_ + ni * 16 + l15) * NLP) + l16 * 8);
            pa[ni] = __builtin_amdgcn_mfma_f32_16x16x32_bf16(af, bfr, pa[ni], 0, 0, 0);
        }
        // D-frag (row=l16*4+jj, col=ni*16+l15) -> LDS with bias
#pragma unroll
        for (int ni = 0; ni < 4; ++ni) {
            const float bv = bd[r * NP_ + ni * 16 + l15];
#pragma unroll
            for (int jj = 0; jj < 4; ++jj)
                pt[w][l16 * 4 + jj][ni * 16 + l15] = pa[ni][jj] + bv;
        }
        __syncthreads();
        // coalesced writeback: 16-lane group owns one full 256B row-slice
#pragma unroll
        for (int it = 0; it < 4; ++it) {
            const int row = it * 4 + l16;
            const float4 v = *reinterpret_cast<const float4*>(&pt[w][row][l15 * 4]);
            const size_t gi = (size_t)(row0 + row) * N_ + r * NP_ + l15 * 4;
            const float4 tg = *reinterpret_cast<const float4*>(tgt + gi);
            *reinterpret_cast<float4*>(preds + gi) = v;
            lsum += (__expf(v.x) - tg.x * v.x) + (__expf(v.y) - tg.y * v.y)
                  + (__expf(v.z) - tg.z * v.z) + (__expf(v.w) - tg.w * v.w);
        }
        __syncthreads();
    }
#pragma unroll
    for (int off = 32; off; off >>= 1) lsum += __shfl_down(lsum, off);
    __shared__ float red[4];
    if ((tid & 63) == 0) red[tid >> 6] = lsum;
    __syncthreads();
    if (tid == 0) atomicAdd(acc, red[0] + red[1] + red[2] + red[3]);
}

// reg partial: sum |diff(lat_pad)| (pad cols diff to exactly 0)
__global__ __launch_bounds__(256) void k_reg(const ushort* __restrict__ latp,
                                             float* __restrict__ acc) {
    const int total8 = BT_ * (LPAD / 8);
    float rsum = 0.f;
    for (int i8 = blockIdx.x * 256 + threadIdx.x; i8 < total8; i8 += gridDim.x * 256) {
        const int row = i8 >> 6;
        if ((row & (T_ - 1)) == T_ - 1) continue;
        const bf16x8 v0 = *reinterpret_cast<const bf16x8*>(latp + (size_t)i8 * 8);
        const bf16x8 v1 = *reinterpret_cast<const bf16x8*>(latp + (size_t)(i8 + 64) * 8);
#pragma unroll
        for (int jj = 0; jj < 8; ++jj)
            rsum += fabsf(bf2f((ushort)v1[jj]) - bf2f((ushort)v0[jj]));
    }
#pragma unroll
    for (int off = 32; off; off >>= 1) rsum += __shfl_down(rsum, off);
    __shared__ float red[4];
    if ((threadIdx.x & 63) == 0) red[threadIdx.x >> 6] = rsum;
    __syncthreads();
    if (threadIdx.x == 0) atomicAdd(acc + 1, red[0] + red[1] + red[2] + red[3]);
}

__global__ void k_fin(const float* __restrict__ acc, float* __restrict__ out) {
    if (threadIdx.x == 0) {
        out[0] = acc[0] * (1.0f / ((float)BT_ * N_));
        out[1] = acc[1] * (0.1f / ((float)B_ * (T_ - 1) * RNL));
    }
}

extern "C" void kernel_launch(void* const* d_in, const int* in_sizes, int n_in,
                              void* d_out, int out_size, void* d_ws, size_t ws_size,
                              hipStream_t stream) {
    const float* spikes = (const float*)d_in[0];
    const int*   keep   = (const int*)d_in[2];
    const float* Wst    = (const float*)d_in[3];
    const float* bst    = (const float*)d_in[4];
    const float* Wu     = (const float*)d_in[5];
    const float* bu     = (const float*)d_in[6];
    const float* Wv     = (const float*)d_in[7];
    const float* bv     = (const float*)d_in[8];
    const float* Wd     = (const float*)d_in[9];
    const float* bd     = (const float*)d_in[10];
    float* out = (float*)d_out;
    float* ws  = (float*)d_ws;

    float* Wcomb = ws + OFF_WCOMB;
    float* bcomb = ws + OFF_BCOMB;
    float* Amat  = ws + OFF_AMAT;
    float* cvec  = ws + OFF_CVEC;
    float* acc   = ws + OFF_ACC;
    ushort* ush   = (ushort*)(ws + OFF_USH);
    ushort* AmatT = ush + UOFF_AMATT;
    ushort* WdT   = ush + UOFF_WDT;
    ushort* latp  = ush + UOFF_LATP;

    k_comb<<<(N_ * H_) / 256, 256, 0, stream>>>(Wst, Wu, keep, Wcomb, acc);
    k_bcomb<<<H_, 256, 0, stream>>>(bst, Wu, bu, keep, bcomb);
    k_cvec<<<RNL, 256, 0, stream>>>(bcomb, Wv, bv, cvec);
    gemm_bias<<<dim3(RNL / 64, N_ / 128), 256, 0, stream>>>(Wcomb, Wv, Amat, N_, RNL, H_);
    k_castA<<<(RNL * N_) / 256, 256, 0, stream>>>(Amat, AmatT);
    k_castWd<<<(R_ * NP_ * NLP) / 256, 256, 0, stream>>>(Wd, WdT);
    gemm_mfma<<<1280, 256, 0, stream>>>(spikes, AmatT, cvec, latp);
    k_dec<<<BT_ / 16, 256, 0, stream>>>(latp, WdT, bd, spikes, out + 2, acc);
    k_reg<<<2048, 256, 0, stream>>>(latp, acc);
    k_fin<<<1, 64, 0, stream>>>(acc, out);
}